// Round 8
// baseline (382.492 us; speedup 1.0000x reference)
//
#include <hip/hip_runtime.h>
#include <math.h>

#define B_ROWS 2048
#define P_ROWS 100000
#define D_DIM  128
#define NPC    128                // pool chunks (grid.x of gemm)
#define NT     782                // ceil(100000/128) pool tiles
#define TILEB  32768              // 128 pool-rows x 128 bf16 (256 B/row)
#define NCAND  (NPC * 3)          // 384 screened candidates per row

typedef short short8 __attribute__((ext_vector_type(8)));
typedef float f32x4  __attribute__((ext_vector_type(4)));
typedef unsigned long long u64;

// bf16 RNE
__device__ __forceinline__ unsigned short f2bf(float f) {
    unsigned u = __float_as_uint(f);
    u += 0x7fffu + ((u >> 16) & 1u);
    return (unsigned short)(u >> 16);
}

__device__ __forceinline__ void async16(const char* g, char* l) {
    __builtin_amdgcn_global_load_lds(
        (const __attribute__((address_space(1))) unsigned int*)g,
        (__attribute__((address_space(3))) unsigned int*)l,
        16, 0, 0);
}

// u64 branchless top-3 insert (merge path only, outside hot loop)
__device__ __forceinline__ void kins64(u64 k, u64& t0, u64& t1, u64& t2) {
    u64 m0 = (t0 < k) ? t0 : k;  t0 = (t0 < k) ? k : t0;
    u64 m1 = (t1 < m0) ? t1 : m0; t1 = (t1 < m0) ? m0 : t1;
    t2 = (t2 < m1) ? m1 : t2;
}

// fp64 top-3 insert with index tie-break (lower index wins)
__device__ __forceinline__ void ins3d(double v, int c,
                                      double& v0, int& i0,
                                      double& v1, int& i1,
                                      double& v2, int& i2) {
    bool b0 = (v > v0) || (v == v0 && c < i0);
    bool b1 = (v > v1) || (v == v1 && c < i1);
    bool b2 = (v > v2) || (v == v2 && c < i2);
    if (b0)      { v2 = v1; i2 = i1; v1 = v0; i1 = i0; v0 = v; i0 = c; }
    else if (b1) { v2 = v1; i2 = i1; v1 = v;  i1 = c; }
    else if (b2) { v2 = v;  i2 = c; }
}

// ---------------------------------------------------------------------------
// Kernel 1: pack sess -> hi-bf16, linear 256 B/row. One wave per row.
// Block 0 also zeroes S (runs before pack_pool on the same stream).
// ---------------------------------------------------------------------------
__global__ void pack_sess_kernel(const float* __restrict__ sess,
                                 char* __restrict__ sess2,
                                 float* __restrict__ S) {
    if (blockIdx.x == 0 && threadIdx.x < 128) S[threadIdx.x] = 0.f;
    int row  = blockIdx.x * 4 + (threadIdx.x >> 6);
    int lane = threadIdx.x & 63;
    float2 v = ((const float2*)(sess + (size_t)row * D_DIM))[lane];
    float s = v.x * v.x + v.y * v.y;
    #pragma unroll
    for (int o = 32; o > 0; o >>= 1) s += __shfl_xor(s, o);
    float inv = 1.0f / sqrtf(s + (float)D_DIM * 1e-6f);
    ushort2 hv;
    hv.x = f2bf(v.x * inv);
    hv.y = f2bf(v.y * inv);
    *(ushort2*)(sess2 + (size_t)row * 256 + lane * 4) = hv;
}

// ---------------------------------------------------------------------------
// Kernel 2: pack pool -> pool2[T][c][slot][16B] hi-bf16, XOR-swizzled
// (logical group g stored at slot g^(c&7)); fused norms; OOB rows -> zeros;
// S[d] += sum of normalized values per dim (atomic, fp32).
// ---------------------------------------------------------------------------
__global__ void pack_pool_kernel(const float* __restrict__ pool,
                                 char* __restrict__ pool2,
                                 float* __restrict__ S) {
    __shared__ float red[128][17];
    __shared__ float s_inv[128];
    __shared__ float red2[16][128];
    const int tid = threadIdx.x;
    const int T   = blockIdx.x;

    float4 d[8][2];
    #pragma unroll
    for (int it = 0; it < 8; ++it) {
        int c = it * 16 + (tid >> 4), g = tid & 15;
        int n = T * 128 + c;
        float4 a = make_float4(0.f, 0.f, 0.f, 0.f), b = a;
        if (n < P_ROWS) {
            const float4* src = (const float4*)(pool + (size_t)n * D_DIM + g * 8);
            a = src[0]; b = src[1];
        }
        d[it][0] = a; d[it][1] = b;
        red[c][g] = a.x*a.x + a.y*a.y + a.z*a.z + a.w*a.w
                  + b.x*b.x + b.y*b.y + b.z*b.z + b.w*b.w;
    }
    __syncthreads();
    if (tid < 128) {
        float s = 0.f;
        #pragma unroll
        for (int j = 0; j < 16; ++j) s += red[tid][j];
        s_inv[tid] = 1.0f / sqrtf(s + (float)D_DIM * 1e-6f);
    }
    __syncthreads();

    float sacc[8] = {0.f,0.f,0.f,0.f,0.f,0.f,0.f,0.f};
    const int g = tid & 15;
    #pragma unroll
    for (int it = 0; it < 8; ++it) {
        int c = it * 16 + (tid >> 4);
        float inv = s_inv[c];
        const float* f = (const float*)&d[it][0];
        short8 hv;
        #pragma unroll
        for (int j = 0; j < 8; ++j) {
            float w = f[j] * inv;
            hv[j] = (short)f2bf(w);
            sacc[j] += w;
        }
        *(short8*)(pool2 + (size_t)T * TILEB + c * 256 + ((g ^ (c & 7)) * 16)) = hv;
    }
    #pragma unroll
    for (int j = 0; j < 8; ++j) red2[tid >> 4][g * 8 + j] = sacc[j];
    __syncthreads();
    if (tid < 128) {
        float s = 0.f;
        #pragma unroll
        for (int k = 0; k < 16; ++k) s += red2[k][tid];
        atomicAdd(&S[tid], s);
    }
}

// ---------------------------------------------------------------------------
// Kernel 3: hi-bf16 MFMA cosine SCREEN, top-3 keys only (no z).
// Grid (NPC, 8) = 1024 blocks -> 4 blocks/CU, 16 waves/CU. Block 256 = 4
// waves. M-tile 256 rows; wave: 64 rows x 128 cols. A stationary in regs
// (K=128, 64 VGPR). B via global_load_lds (32 KB tile). Col loop in quarters.
// Within-lane key = fp32 v, low 7 mantissa bits := pos (tloc*8+colsub<=55);
// Merge key = u64: monotone(f32 bits)<<32 | (131071-col) -> exact order,
// lower-index tie-break under max-merge.
// ---------------------------------------------------------------------------
__launch_bounds__(256, 4)
__global__ void gemm_topk_kernel(const char* __restrict__ sess2,
                                 const char* __restrict__ pool2,
                                 u64* __restrict__ partials) {
    __shared__ char lds[TILEB];

    const int tid = threadIdx.x;
    const int w   = tid >> 6;
    const int L   = tid & 63;
    const int q   = L >> 4;
    const int l15 = L & 15;
    const int l7  = L & 7;
    const int pc  = blockIdx.x;
    const int mt  = blockIdx.y;
    const int rowbase = mt * 256 + w * 64;

    short8 afrag[4][4];
    #pragma unroll
    for (int i = 0; i < 4; ++i)
        #pragma unroll
        for (int ks = 0; ks < 4; ++ks)
            afrag[i][ks] = *(const short8*)(sess2 +
                (size_t)(rowbase + i * 16 + l15) * 256 + (ks * 4 + q) * 16);

    // hoisted XOR-swizzled K-slot offsets (invariant across tiles)
    int soks[4];
    #pragma unroll
    for (int ks = 0; ks < 4; ++ks) soks[ks] = ((ks * 4 + q) ^ l7) * 16;
    const char* lbase = lds + l15 * 256;

    float key0[4][4], key1[4][4], key2[4][4];
    #pragma unroll
    for (int i = 0; i < 4; ++i)
        #pragma unroll
        for (int r = 0; r < 4; ++r)
            key0[i][r] = key1[i][r] = key2[i][r] = -1e30f;

    int tloc = 0;
    for (int T = pc; T < NT; T += NPC, ++tloc) {
        __syncthreads();
        const char* tb = pool2 + (size_t)T * TILEB;
        #pragma unroll
        for (int rr = 0; rr < 8; ++rr) {
            int idx = rr * 256 + tid;
            async16(tb + idx * 16, lds + idx * 16);
        }
        __syncthreads();

        #pragma unroll
        for (int qt = 0; qt < 4; ++qt) {
            f32x4 acc[4][2];
            #pragma unroll
            for (int i = 0; i < 4; ++i) {
                acc[i][0] = (f32x4){0.f,0.f,0.f,0.f};
                acc[i][1] = (f32x4){0.f,0.f,0.f,0.f};
            }
            #pragma unroll
            for (int ks = 0; ks < 4; ++ks) {
                const char* cb = lbase + qt * 8192 + soks[ks];
                short8 b0 = *(const short8*)(cb);
                short8 b1 = *(const short8*)(cb + 16 * 256);
                #pragma unroll
                for (int i = 0; i < 4; ++i) {
                    acc[i][0] = __builtin_amdgcn_mfma_f32_16x16x32_bf16(
                        afrag[i][ks], b0, acc[i][0], 0, 0, 0);
                    acc[i][1] = __builtin_amdgcn_mfma_f32_16x16x32_bf16(
                        afrag[i][ks], b1, acc[i][1], 0, 0, 0);
                }
            }
            #pragma unroll
            for (int j = 0; j < 2; ++j) {
                const unsigned pos = (unsigned)(tloc * 8 + qt * 2 + j);
                #pragma unroll
                for (int i = 0; i < 4; ++i)
                    #pragma unroll
                    for (int r = 0; r < 4; ++r) {
                        float v = acc[i][j][r];
                        float kf = __uint_as_float(
                            (__float_as_uint(v) & 0xFFFFFF80u) | pos);
                        float o0 = key0[i][r], o1 = key1[i][r];
                        key0[i][r] = fmaxf(o0, kf);
                        key1[i][r] = __builtin_amdgcn_fmed3f(kf, o0, key1[i][r]);
                        key2[i][r] = __builtin_amdgcn_fmed3f(kf, o1, key2[i][r]);
                    }
            }
        }
    }

    // decode -> u64 exact keys, butterfly-merge over the 16 lanes per row
    #pragma unroll
    for (int i = 0; i < 4; ++i)
        #pragma unroll
        for (int r = 0; r < 4; ++r) {
            float kk[3] = {key0[i][r], key1[i][r], key2[i][r]};
            u64 t0 = 0ull, t1 = 0ull, t2 = 0ull;
            #pragma unroll
            for (int k = 0; k < 3; ++k) {
                unsigned u   = __float_as_uint(kk[k]);
                unsigned pos = u & 127u;
                unsigned vb  = u & 0xFFFFFF80u;
                unsigned mono = (vb & 0x80000000u) ? ~vb : (vb | 0x80000000u);
                unsigned col = (unsigned)((pc + (int)(pos >> 3) * NPC) * 128
                                          + (int)(pos & 7u) * 16 + l15);
                u64 key = ((u64)mono << 32) | (u64)(131071u - col);
                kins64(key, t0, t1, t2);
            }
            #pragma unroll
            for (int m = 1; m < 16; m <<= 1) {
                u64 r0 = __shfl_xor(t0, m);
                u64 r1 = __shfl_xor(t1, m);
                u64 r2 = __shfl_xor(t2, m);
                kins64(r0, t0, t1, t2);
                kins64(r1, t0, t1, t2);
                kins64(r2, t0, t1, t2);
            }
            if (l15 == 0) {
                int row = rowbase + i * 16 + q * 4 + r;
                u64* o = partials + ((size_t)row * NPC + pc) * 3;
                o[0] = t0; o[1] = t1; o[2] = t2;
            }
        }
}

// ---------------------------------------------------------------------------
// Kernel 4: per row (one wave) — merge 384 exact-screen u64 keys -> top-8,
// fp64 rescore ONLY those 8, exact top-3 (index tie-break), moment-z,
// double softmax, gather, write. 4 rows per 256-thr block, no LDS/sync.
// ---------------------------------------------------------------------------
__launch_bounds__(256)
__global__ void finalize_kernel(const float* __restrict__ sess,
                                const float* __restrict__ pool,
                                const u64* __restrict__ partials,
                                const float* __restrict__ S,
                                float* __restrict__ out_neighbor,
                                float* __restrict__ out_costopk,
                                float* __restrict__ out_sesstopk) {
    const int row = blockIdx.x * 4 + (threadIdx.x >> 6);
    const int L   = threadIdx.x & 63;

    // 6 keys per lane = 2 chunk-triples (each stored descending)
    const u64* pk = partials + (size_t)row * NCAND + 6 * L;
    u64 t0 = pk[0], t1 = pk[1], t2 = pk[2];
    kins64(pk[3], t0, t1, t2);
    kins64(pk[4], t0, t1, t2);
    kins64(pk[5], t0, t1, t2);

    // extract global top-8 by screen order (keys unique via col bits)
    u64 cand[8];
    #pragma unroll
    for (int k = 0; k < 8; ++k) {
        u64 m = t0;
        #pragma unroll
        for (int o = 1; o < 64; o <<= 1) {
            u64 r = __shfl_xor(m, o);
            m = (r > m) ? r : m;
        }
        cand[k] = m;
        if (t0 == m) { t0 = t1; t1 = t2; t2 = 0ull; }
    }

    // gather the 8 candidate rows (independent loads, issued together)
    const float2 sa = ((const float2*)(sess + (size_t)row * D_DIM))[L];
    int    idx[8];
    float2 pb[8];
    #pragma unroll
    for (int j = 0; j < 8; ++j) {
        idx[j] = 131071 - (int)(cand[j] & 0x1FFFFull);
        bool ok = idx[j] < P_ROWS;
        pb[j] = ok ? ((const float2*)(pool + (size_t)idx[j] * D_DIM))[L]
                   : make_float2(0.f, 0.f);
    }

    // na and moment-z dot in one butterfly pass
    double na  = (double)sa.x * sa.x + (double)sa.y * sa.y;
    double dss = (double)sa.x * S[2 * L] + (double)sa.y * S[2 * L + 1];
    #pragma unroll
    for (int o = 32; o > 0; o >>= 1) {
        na  += __shfl_xor(na, o);
        dss += __shfl_xor(dss, o);
    }
    na += (double)D_DIM * 1e-6;

    // fp64 rescore of the 8 candidates
    double v[8];
    #pragma unroll
    for (int j = 0; j < 8; ++j) {
        double dot = (double)sa.x * pb[j].x + (double)sa.y * pb[j].y;
        double nb  = (double)pb[j].x * pb[j].x + (double)pb[j].y * pb[j].y;
        #pragma unroll
        for (int o = 32; o > 0; o >>= 1) {
            dot += __shfl_xor(dot, o);
            nb  += __shfl_xor(nb, o);
        }
        v[j] = (idx[j] < P_ROWS)
             ? dot / sqrt(na * (nb + (double)D_DIM * 1e-6))
             : -1e300;
    }

    // exact top-3 of the 8 (all lanes redundantly; values identical)
    double v0 = -1e300, v1 = -1e300, v2 = -1e300;
    int    i0 = 0x7fffffff, i1 = 0x7fffffff, i2 = 0x7fffffff;
    #pragma unroll
    for (int j = 0; j < 8; ++j) ins3d(v[j], idx[j], v0, i0, v1, i1, v2, i2);

    // z = P + s^.S + 0.5*E[sum v^2]  (moment expansion of sum exp(v))
    double z  = (double)P_ROWS + dss / sqrt(na) + 390.625;
    double c0 = exp(v0) / z, c1 = exp(v1) / z, c2 = exp(v2) / z;
    double e1 = exp(c1 - c0), e2 = exp(c2 - c0);
    double inv = 1.0 / (1.0 + e1 + e2);
    float  w0 = (float)inv, w1 = (float)(e1 * inv), w2 = (float)(e2 * inv);

    // gather winners + write all outputs
    float2 g0 = ((const float2*)(pool + (size_t)i0 * D_DIM))[L];
    float2 g1 = ((const float2*)(pool + (size_t)i1 * D_DIM))[L];
    float2 g2 = ((const float2*)(pool + (size_t)i2 * D_DIM))[L];
    ((float2*)(out_sesstopk + ((size_t)row * 3 + 0) * D_DIM))[L] = g0;
    ((float2*)(out_sesstopk + ((size_t)row * 3 + 1) * D_DIM))[L] = g1;
    ((float2*)(out_sesstopk + ((size_t)row * 3 + 2) * D_DIM))[L] = g2;
    float2 nbv;
    nbv.x = w0 * g0.x + w1 * g1.x + w2 * g2.x;
    nbv.y = w0 * g0.y + w1 * g1.y + w2 * g2.y;
    ((float2*)(out_neighbor + (size_t)row * D_DIM))[L] = nbv;
    if (L == 0) {
        out_costopk[row * 3 + 0] = w0;
        out_costopk[row * 3 + 1] = w1;
        out_costopk[row * 3 + 2] = w2;
    }
}

// ---------------------------------------------------------------------------
extern "C" void kernel_launch(void* const* d_in, const int* in_sizes, int n_in,
                              void* d_out, int out_size, void* d_ws, size_t ws_size,
                              hipStream_t stream) {
    const float* sess = (const float*)d_in[0];   // [2048,128]
    const float* pool = (const float*)d_in[1];   // [100000,128]
    float* out = (float*)d_out;
    float* out_neighbor = out;
    float* out_costopk  = out + (size_t)B_ROWS * D_DIM;
    float* out_sesstopk = out_costopk + (size_t)B_ROWS * 3;

    // workspace: S (512B) | partials (6.3MB) | sess2 (512KB) | pool2 (25.6MB)
    float* Svec     = (float*)d_ws;
    u64*   partials = (u64*)((char*)d_ws + 512);
    char*  sess2    = (char*)d_ws + 512 + (size_t)B_ROWS * NCAND * 8;
    char*  pool2    = sess2 + (size_t)B_ROWS * 256;

    pack_sess_kernel<<<B_ROWS / 4, 256, 0, stream>>>(sess, sess2, Svec);
    pack_pool_kernel<<<NT, 256, 0, stream>>>(pool, pool2, Svec);

    dim3 g3(NPC, B_ROWS / 256);
    gemm_topk_kernel<<<g3, 256, 0, stream>>>(sess2, pool2, partials);

    finalize_kernel<<<B_ROWS / 4, 256, 0, stream>>>(
        sess, pool, partials, Svec, out_neighbor, out_costopk, out_sesstopk);
}

// Round 9
// 227.141 us; speedup vs baseline: 1.6839x; 1.6839x over previous
//
#include <hip/hip_runtime.h>
#include <math.h>

#define B_ROWS 2048
#define P_ROWS 100000
#define D_DIM  128
#define NPC    128                // pool chunks (grid.x of gemm)
#define NT     782                // ceil(100000/128) pool tiles
#define TILEB  32768              // 128 pool-rows x 128 bf16 (256 B/row)
#define NCAND  (NPC * 3)          // 384 screened candidates per row

typedef short short8 __attribute__((ext_vector_type(8)));
typedef float f32x4  __attribute__((ext_vector_type(4)));
typedef unsigned long long u64;

// bf16 RNE
__device__ __forceinline__ unsigned short f2bf(float f) {
    unsigned u = __float_as_uint(f);
    u += 0x7fffu + ((u >> 16) & 1u);
    return (unsigned short)(u >> 16);
}

__device__ __forceinline__ void async16(const char* g, char* l) {
    __builtin_amdgcn_global_load_lds(
        (const __attribute__((address_space(1))) unsigned int*)g,
        (__attribute__((address_space(3))) unsigned int*)l,
        16, 0, 0);
}

// u64 branchless top-3 insert (merge path only, outside hot loop)
__device__ __forceinline__ void kins64(u64 k, u64& t0, u64& t1, u64& t2) {
    u64 m0 = (t0 < k) ? t0 : k;  t0 = (t0 < k) ? k : t0;
    u64 m1 = (t1 < m0) ? t1 : m0; t1 = (t1 < m0) ? m0 : t1;
    t2 = (t2 < m1) ? m1 : t2;
}

// fp64 top-3 insert with index tie-break (lower index wins)
__device__ __forceinline__ void ins3d(double v, int c,
                                      double& v0, int& i0,
                                      double& v1, int& i1,
                                      double& v2, int& i2) {
    bool b0 = (v > v0) || (v == v0 && c < i0);
    bool b1 = (v > v1) || (v == v1 && c < i1);
    bool b2 = (v > v2) || (v == v2 && c < i2);
    if (b0)      { v2 = v1; i2 = i1; v1 = v0; i1 = i0; v0 = v; i0 = c; }
    else if (b1) { v2 = v1; i2 = i1; v1 = v;  i1 = c; }
    else if (b2) { v2 = v;  i2 = c; }
}

// ---------------------------------------------------------------------------
// Kernel 1: pack sess -> hi-bf16, linear 256 B/row. One wave per row.
// Block 0 also zeroes S (runs before pack_pool on the same stream).
// ---------------------------------------------------------------------------
__global__ void pack_sess_kernel(const float* __restrict__ sess,
                                 char* __restrict__ sess2,
                                 float* __restrict__ S) {
    if (blockIdx.x == 0 && threadIdx.x < 128) S[threadIdx.x] = 0.f;
    int row  = blockIdx.x * 4 + (threadIdx.x >> 6);
    int lane = threadIdx.x & 63;
    float2 v = ((const float2*)(sess + (size_t)row * D_DIM))[lane];
    float s = v.x * v.x + v.y * v.y;
    #pragma unroll
    for (int o = 32; o > 0; o >>= 1) s += __shfl_xor(s, o);
    float inv = 1.0f / sqrtf(s + (float)D_DIM * 1e-6f);
    ushort2 hv;
    hv.x = f2bf(v.x * inv);
    hv.y = f2bf(v.y * inv);
    *(ushort2*)(sess2 + (size_t)row * 256 + lane * 4) = hv;
}

// ---------------------------------------------------------------------------
// Kernel 2: pack pool -> pool2[T][c][slot][16B] hi-bf16, XOR-swizzled
// (logical group g stored at slot g^(c&7)); fused norms; OOB rows -> zeros;
// S[d] += sum of normalized values per dim (atomic, fp32).
// ---------------------------------------------------------------------------
__global__ void pack_pool_kernel(const float* __restrict__ pool,
                                 char* __restrict__ pool2,
                                 float* __restrict__ S) {
    __shared__ float red[128][17];
    __shared__ float s_inv[128];
    __shared__ float red2[16][128];
    const int tid = threadIdx.x;
    const int T   = blockIdx.x;

    float4 d[8][2];
    #pragma unroll
    for (int it = 0; it < 8; ++it) {
        int c = it * 16 + (tid >> 4), g = tid & 15;
        int n = T * 128 + c;
        float4 a = make_float4(0.f, 0.f, 0.f, 0.f), b = a;
        if (n < P_ROWS) {
            const float4* src = (const float4*)(pool + (size_t)n * D_DIM + g * 8);
            a = src[0]; b = src[1];
        }
        d[it][0] = a; d[it][1] = b;
        red[c][g] = a.x*a.x + a.y*a.y + a.z*a.z + a.w*a.w
                  + b.x*b.x + b.y*b.y + b.z*b.z + b.w*b.w;
    }
    __syncthreads();
    if (tid < 128) {
        float s = 0.f;
        #pragma unroll
        for (int j = 0; j < 16; ++j) s += red[tid][j];
        s_inv[tid] = 1.0f / sqrtf(s + (float)D_DIM * 1e-6f);
    }
    __syncthreads();

    float sacc[8] = {0.f,0.f,0.f,0.f,0.f,0.f,0.f,0.f};
    const int g = tid & 15;
    #pragma unroll
    for (int it = 0; it < 8; ++it) {
        int c = it * 16 + (tid >> 4);
        float inv = s_inv[c];
        const float* f = (const float*)&d[it][0];
        short8 hv;
        #pragma unroll
        for (int j = 0; j < 8; ++j) {
            float w = f[j] * inv;
            hv[j] = (short)f2bf(w);
            sacc[j] += w;
        }
        *(short8*)(pool2 + (size_t)T * TILEB + c * 256 + ((g ^ (c & 7)) * 16)) = hv;
    }
    #pragma unroll
    for (int j = 0; j < 8; ++j) red2[tid >> 4][g * 8 + j] = sacc[j];
    __syncthreads();
    if (tid < 128) {
        float s = 0.f;
        #pragma unroll
        for (int k = 0; k < 16; ++k) s += red2[k][tid];
        atomicAdd(&S[tid], s);
    }
}

// ---------------------------------------------------------------------------
// Kernel 3: hi-bf16 MFMA cosine SCREEN, top-3 keys only (no z).
// Grid (NPC, 8) = 1024 blocks -> 4 blocks/CU (runtime-packed: 88 VGPR allows
// 5 waves/EU, LDS 32KB allows 5 blocks/CU). Block 256 = 4 waves. M-tile 256
// rows; wave: 64 rows x 128 cols. A stationary in regs (K=128, 64 VGPR).
// B via global_load_lds. Col loop in quarters.
// NOTE: launch_bounds MUST stay (256,2) — (256,4) makes the allocator target
// 64 VGPR and spill ~850 MB of scratch per launch (R8: 2.7x regression).
// Within-lane key = fp32 v, low 7 mantissa bits := pos (tloc*8+colsub<=55);
// Merge key = u64: monotone(f32 bits)<<32 | (131071-col) -> exact order,
// lower-index tie-break under max-merge.
// ---------------------------------------------------------------------------
__launch_bounds__(256, 2)
__global__ void gemm_topk_kernel(const char* __restrict__ sess2,
                                 const char* __restrict__ pool2,
                                 u64* __restrict__ partials) {
    __shared__ char lds[TILEB];

    const int tid = threadIdx.x;
    const int w   = tid >> 6;
    const int L   = tid & 63;
    const int q   = L >> 4;
    const int l15 = L & 15;
    const int l7  = L & 7;
    const int pc  = blockIdx.x;
    const int mt  = blockIdx.y;
    const int rowbase = mt * 256 + w * 64;

    short8 afrag[4][4];
    #pragma unroll
    for (int i = 0; i < 4; ++i)
        #pragma unroll
        for (int ks = 0; ks < 4; ++ks)
            afrag[i][ks] = *(const short8*)(sess2 +
                (size_t)(rowbase + i * 16 + l15) * 256 + (ks * 4 + q) * 16);

    // hoisted XOR-swizzled K-slot offsets (invariant across tiles)
    int soks[4];
    #pragma unroll
    for (int ks = 0; ks < 4; ++ks) soks[ks] = ((ks * 4 + q) ^ l7) * 16;
    const char* lbase = lds + l15 * 256;

    float key0[4][4], key1[4][4], key2[4][4];
    #pragma unroll
    for (int i = 0; i < 4; ++i)
        #pragma unroll
        for (int r = 0; r < 4; ++r)
            key0[i][r] = key1[i][r] = key2[i][r] = -1e30f;

    int tloc = 0;
    for (int T = pc; T < NT; T += NPC, ++tloc) {
        __syncthreads();
        const char* tb = pool2 + (size_t)T * TILEB;
        #pragma unroll
        for (int rr = 0; rr < 8; ++rr) {
            int idx = rr * 256 + tid;
            async16(tb + idx * 16, lds + idx * 16);
        }
        __syncthreads();

        #pragma unroll
        for (int qt = 0; qt < 4; ++qt) {
            f32x4 acc[4][2];
            #pragma unroll
            for (int i = 0; i < 4; ++i) {
                acc[i][0] = (f32x4){0.f,0.f,0.f,0.f};
                acc[i][1] = (f32x4){0.f,0.f,0.f,0.f};
            }
            #pragma unroll
            for (int ks = 0; ks < 4; ++ks) {
                const char* cb = lbase + qt * 8192 + soks[ks];
                short8 b0 = *(const short8*)(cb);
                short8 b1 = *(const short8*)(cb + 16 * 256);
                #pragma unroll
                for (int i = 0; i < 4; ++i) {
                    acc[i][0] = __builtin_amdgcn_mfma_f32_16x16x32_bf16(
                        afrag[i][ks], b0, acc[i][0], 0, 0, 0);
                    acc[i][1] = __builtin_amdgcn_mfma_f32_16x16x32_bf16(
                        afrag[i][ks], b1, acc[i][1], 0, 0, 0);
                }
            }
            #pragma unroll
            for (int j = 0; j < 2; ++j) {
                const unsigned pos = (unsigned)(tloc * 8 + qt * 2 + j);
                #pragma unroll
                for (int i = 0; i < 4; ++i)
                    #pragma unroll
                    for (int r = 0; r < 4; ++r) {
                        float v = acc[i][j][r];
                        float kf = __uint_as_float(
                            (__float_as_uint(v) & 0xFFFFFF80u) | pos);
                        float o0 = key0[i][r], o1 = key1[i][r];
                        key0[i][r] = fmaxf(o0, kf);
                        key1[i][r] = __builtin_amdgcn_fmed3f(kf, o0, key1[i][r]);
                        key2[i][r] = __builtin_amdgcn_fmed3f(kf, o1, key2[i][r]);
                    }
            }
        }
    }

    // decode -> u64 exact keys, butterfly-merge over the 16 lanes per row
    #pragma unroll
    for (int i = 0; i < 4; ++i)
        #pragma unroll
        for (int r = 0; r < 4; ++r) {
            float kk[3] = {key0[i][r], key1[i][r], key2[i][r]};
            u64 t0 = 0ull, t1 = 0ull, t2 = 0ull;
            #pragma unroll
            for (int k = 0; k < 3; ++k) {
                unsigned u   = __float_as_uint(kk[k]);
                unsigned pos = u & 127u;
                unsigned vb  = u & 0xFFFFFF80u;
                unsigned mono = (vb & 0x80000000u) ? ~vb : (vb | 0x80000000u);
                unsigned col = (unsigned)((pc + (int)(pos >> 3) * NPC) * 128
                                          + (int)(pos & 7u) * 16 + l15);
                u64 key = ((u64)mono << 32) | (u64)(131071u - col);
                kins64(key, t0, t1, t2);
            }
            #pragma unroll
            for (int m = 1; m < 16; m <<= 1) {
                u64 r0 = __shfl_xor(t0, m);
                u64 r1 = __shfl_xor(t1, m);
                u64 r2 = __shfl_xor(t2, m);
                kins64(r0, t0, t1, t2);
                kins64(r1, t0, t1, t2);
                kins64(r2, t0, t1, t2);
            }
            if (l15 == 0) {
                int row = rowbase + i * 16 + q * 4 + r;
                u64* o = partials + ((size_t)row * NPC + pc) * 3;
                o[0] = t0; o[1] = t1; o[2] = t2;
            }
        }
}

// ---------------------------------------------------------------------------
// Kernel 4: per row (one wave) — merge 384 exact-screen u64 keys -> top-8,
// fp64 rescore ONLY those 8, exact top-3 (index tie-break), moment-z,
// double softmax, gather, write. 4 rows per 256-thr block, no LDS/sync.
// ---------------------------------------------------------------------------
__launch_bounds__(256)
__global__ void finalize_kernel(const float* __restrict__ sess,
                                const float* __restrict__ pool,
                                const u64* __restrict__ partials,
                                const float* __restrict__ S,
                                float* __restrict__ out_neighbor,
                                float* __restrict__ out_costopk,
                                float* __restrict__ out_sesstopk) {
    const int row = blockIdx.x * 4 + (threadIdx.x >> 6);
    const int L   = threadIdx.x & 63;

    // 6 keys per lane = 2 chunk-triples (each stored descending)
    const u64* pk = partials + (size_t)row * NCAND + 6 * L;
    u64 t0 = pk[0], t1 = pk[1], t2 = pk[2];
    kins64(pk[3], t0, t1, t2);
    kins64(pk[4], t0, t1, t2);
    kins64(pk[5], t0, t1, t2);

    // extract global top-8 by screen order (keys unique via col bits)
    u64 cand[8];
    #pragma unroll
    for (int k = 0; k < 8; ++k) {
        u64 m = t0;
        #pragma unroll
        for (int o = 1; o < 64; o <<= 1) {
            u64 r = __shfl_xor(m, o);
            m = (r > m) ? r : m;
        }
        cand[k] = m;
        if (t0 == m) { t0 = t1; t1 = t2; t2 = 0ull; }
    }

    // gather the 8 candidate rows (independent loads, issued together)
    const float2 sa = ((const float2*)(sess + (size_t)row * D_DIM))[L];
    int    idx[8];
    float2 pb[8];
    #pragma unroll
    for (int j = 0; j < 8; ++j) {
        idx[j] = 131071 - (int)(cand[j] & 0x1FFFFull);
        bool ok = idx[j] < P_ROWS;
        pb[j] = ok ? ((const float2*)(pool + (size_t)idx[j] * D_DIM))[L]
                   : make_float2(0.f, 0.f);
    }

    // na and moment-z dot in one butterfly pass
    double na  = (double)sa.x * sa.x + (double)sa.y * sa.y;
    double dss = (double)sa.x * S[2 * L] + (double)sa.y * S[2 * L + 1];
    #pragma unroll
    for (int o = 32; o > 0; o >>= 1) {
        na  += __shfl_xor(na, o);
        dss += __shfl_xor(dss, o);
    }
    na += (double)D_DIM * 1e-6;

    // fp64 rescore of the 8 candidates
    double v[8];
    #pragma unroll
    for (int j = 0; j < 8; ++j) {
        double dot = (double)sa.x * pb[j].x + (double)sa.y * pb[j].y;
        double nb  = (double)pb[j].x * pb[j].x + (double)pb[j].y * pb[j].y;
        #pragma unroll
        for (int o = 32; o > 0; o >>= 1) {
            dot += __shfl_xor(dot, o);
            nb  += __shfl_xor(nb, o);
        }
        v[j] = (idx[j] < P_ROWS)
             ? dot / sqrt(na * (nb + (double)D_DIM * 1e-6))
             : -1e300;
    }

    // exact top-3 of the 8 (all lanes redundantly; values identical)
    double v0 = -1e300, v1 = -1e300, v2 = -1e300;
    int    i0 = 0x7fffffff, i1 = 0x7fffffff, i2 = 0x7fffffff;
    #pragma unroll
    for (int j = 0; j < 8; ++j) ins3d(v[j], idx[j], v0, i0, v1, i1, v2, i2);

    // z = P + s^.S + 0.5*E[sum v^2]  (moment expansion of sum exp(v))
    double z  = (double)P_ROWS + dss / sqrt(na) + 390.625;
    double c0 = exp(v0) / z, c1 = exp(v1) / z, c2 = exp(v2) / z;
    double e1 = exp(c1 - c0), e2 = exp(c2 - c0);
    double inv = 1.0 / (1.0 + e1 + e2);
    float  w0 = (float)inv, w1 = (float)(e1 * inv), w2 = (float)(e2 * inv);

    // gather winners + write all outputs
    float2 g0 = ((const float2*)(pool + (size_t)i0 * D_DIM))[L];
    float2 g1 = ((const float2*)(pool + (size_t)i1 * D_DIM))[L];
    float2 g2 = ((const float2*)(pool + (size_t)i2 * D_DIM))[L];
    ((float2*)(out_sesstopk + ((size_t)row * 3 + 0) * D_DIM))[L] = g0;
    ((float2*)(out_sesstopk + ((size_t)row * 3 + 1) * D_DIM))[L] = g1;
    ((float2*)(out_sesstopk + ((size_t)row * 3 + 2) * D_DIM))[L] = g2;
    float2 nbv;
    nbv.x = w0 * g0.x + w1 * g1.x + w2 * g2.x;
    nbv.y = w0 * g0.y + w1 * g1.y + w2 * g2.y;
    ((float2*)(out_neighbor + (size_t)row * D_DIM))[L] = nbv;
    if (L == 0) {
        out_costopk[row * 3 + 0] = w0;
        out_costopk[row * 3 + 1] = w1;
        out_costopk[row * 3 + 2] = w2;
    }
}

// ---------------------------------------------------------------------------
extern "C" void kernel_launch(void* const* d_in, const int* in_sizes, int n_in,
                              void* d_out, int out_size, void* d_ws, size_t ws_size,
                              hipStream_t stream) {
    const float* sess = (const float*)d_in[0];   // [2048,128]
    const float* pool = (const float*)d_in[1];   // [100000,128]
    float* out = (float*)d_out;
    float* out_neighbor = out;
    float* out_costopk  = out + (size_t)B_ROWS * D_DIM;
    float* out_sesstopk = out_costopk + (size_t)B_ROWS * 3;

    // workspace: S (512B) | partials (6.3MB) | sess2 (512KB) | pool2 (25.6MB)
    float* Svec     = (float*)d_ws;
    u64*   partials = (u64*)((char*)d_ws + 512);
    char*  sess2    = (char*)d_ws + 512 + (size_t)B_ROWS * NCAND * 8;
    char*  pool2    = sess2 + (size_t)B_ROWS * 256;

    pack_sess_kernel<<<B_ROWS / 4, 256, 0, stream>>>(sess, sess2, Svec);
    pack_pool_kernel<<<NT, 256, 0, stream>>>(pool, pool2, Svec);

    dim3 g3(NPC, B_ROWS / 256);
    gemm_topk_kernel<<<g3, 256, 0, stream>>>(sess2, pool2, partials);

    finalize_kernel<<<B_ROWS / 4, 256, 0, stream>>>(
        sess, pool, partials, Svec, out_neighbor, out_costopk, out_sesstopk);
}

// Round 10
// 208.615 us; speedup vs baseline: 1.8335x; 1.0888x over previous
//
#include <hip/hip_runtime.h>
#include <math.h>

#define B_ROWS 2048
#define P_ROWS 100000
#define D_DIM  128
#define NPC    64                 // pool chunks (grid.x of gemm)
#define NT     782                // ceil(100000/128) pool tiles
#define TILEB  32768              // 128 pool-rows x 128 bf16 (256 B/row)
#define NCAND  (NPC * 3)          // 192 screened candidates per row

typedef short short8 __attribute__((ext_vector_type(8)));
typedef float f32x4  __attribute__((ext_vector_type(4)));
typedef unsigned long long u64;

// bf16 RNE
__device__ __forceinline__ unsigned short f2bf(float f) {
    unsigned u = __float_as_uint(f);
    u += 0x7fffu + ((u >> 16) & 1u);
    return (unsigned short)(u >> 16);
}

__device__ __forceinline__ void async16(const char* g, char* l) {
    __builtin_amdgcn_global_load_lds(
        (const __attribute__((address_space(1))) unsigned int*)g,
        (__attribute__((address_space(3))) unsigned int*)l,
        16, 0, 0);
}

// u64 branchless top-3 insert (merge path only, outside hot loop)
__device__ __forceinline__ void kins64(u64 k, u64& t0, u64& t1, u64& t2) {
    u64 m0 = (t0 < k) ? t0 : k;  t0 = (t0 < k) ? k : t0;
    u64 m1 = (t1 < m0) ? t1 : m0; t1 = (t1 < m0) ? m0 : t1;
    t2 = (t2 < m1) ? m1 : t2;
}

// fp64 top-3 insert with index tie-break (lower index wins)
__device__ __forceinline__ void ins3d(double v, int c,
                                      double& v0, int& i0,
                                      double& v1, int& i1,
                                      double& v2, int& i2) {
    bool b0 = (v > v0) || (v == v0 && c < i0);
    bool b1 = (v > v1) || (v == v1 && c < i1);
    bool b2 = (v > v2) || (v == v2 && c < i2);
    if (b0)      { v2 = v1; i2 = i1; v1 = v0; i1 = i0; v0 = v; i0 = c; }
    else if (b1) { v2 = v1; i2 = i1; v1 = v;  i1 = c; }
    else if (b2) { v2 = v;  i2 = c; }
}

// ---------------------------------------------------------------------------
// Kernel 1: pack sess -> hi-bf16, linear 256 B/row. One wave per row.
// Block 0 also zeroes S (runs before pack_pool on the same stream).
// ---------------------------------------------------------------------------
__global__ void pack_sess_kernel(const float* __restrict__ sess,
                                 char* __restrict__ sess2,
                                 float* __restrict__ S) {
    if (blockIdx.x == 0 && threadIdx.x < 128) S[threadIdx.x] = 0.f;
    int row  = blockIdx.x * 4 + (threadIdx.x >> 6);
    int lane = threadIdx.x & 63;
    float2 v = ((const float2*)(sess + (size_t)row * D_DIM))[lane];
    float s = v.x * v.x + v.y * v.y;
    #pragma unroll
    for (int o = 32; o > 0; o >>= 1) s += __shfl_xor(s, o);
    float inv = 1.0f / sqrtf(s + (float)D_DIM * 1e-6f);
    ushort2 hv;
    hv.x = f2bf(v.x * inv);
    hv.y = f2bf(v.y * inv);
    *(ushort2*)(sess2 + (size_t)row * 256 + lane * 4) = hv;
}

// ---------------------------------------------------------------------------
// Kernel 2: pack pool -> pool2[T][c][slot][16B] hi-bf16, XOR-swizzled
// (logical group g stored at slot g^(c&7)); fused norms; OOB rows -> zeros;
// S[d] += sum of normalized values per dim (atomic, fp32).
// ---------------------------------------------------------------------------
__global__ void pack_pool_kernel(const float* __restrict__ pool,
                                 char* __restrict__ pool2,
                                 float* __restrict__ S) {
    __shared__ float red[128][17];
    __shared__ float s_inv[128];
    __shared__ float red2[16][128];
    const int tid = threadIdx.x;
    const int T   = blockIdx.x;

    float4 d[8][2];
    #pragma unroll
    for (int it = 0; it < 8; ++it) {
        int c = it * 16 + (tid >> 4), g = tid & 15;
        int n = T * 128 + c;
        float4 a = make_float4(0.f, 0.f, 0.f, 0.f), b = a;
        if (n < P_ROWS) {
            const float4* src = (const float4*)(pool + (size_t)n * D_DIM + g * 8);
            a = src[0]; b = src[1];
        }
        d[it][0] = a; d[it][1] = b;
        red[c][g] = a.x*a.x + a.y*a.y + a.z*a.z + a.w*a.w
                  + b.x*b.x + b.y*b.y + b.z*b.z + b.w*b.w;
    }
    __syncthreads();
    if (tid < 128) {
        float s = 0.f;
        #pragma unroll
        for (int j = 0; j < 16; ++j) s += red[tid][j];
        s_inv[tid] = 1.0f / sqrtf(s + (float)D_DIM * 1e-6f);
    }
    __syncthreads();

    float sacc[8] = {0.f,0.f,0.f,0.f,0.f,0.f,0.f,0.f};
    const int g = tid & 15;
    #pragma unroll
    for (int it = 0; it < 8; ++it) {
        int c = it * 16 + (tid >> 4);
        float inv = s_inv[c];
        const float* f = (const float*)&d[it][0];
        short8 hv;
        #pragma unroll
        for (int j = 0; j < 8; ++j) {
            float w = f[j] * inv;
            hv[j] = (short)f2bf(w);
            sacc[j] += w;
        }
        *(short8*)(pool2 + (size_t)T * TILEB + c * 256 + ((g ^ (c & 7)) * 16)) = hv;
    }
    #pragma unroll
    for (int j = 0; j < 8; ++j) red2[tid >> 4][g * 8 + j] = sacc[j];
    __syncthreads();
    if (tid < 128) {
        float s = 0.f;
        #pragma unroll
        for (int k = 0; k < 16; ++k) s += red2[k][tid];
        atomicAdd(&S[tid], s);
    }
}

// ---------------------------------------------------------------------------
// Kernel 3: hi-bf16 MFMA cosine SCREEN, top-3 keys only (no z).
// Grid (NPC, 16) = 1024 blocks. Block 256 = 4 waves covering 128 rows; each
// wave: 32 rows x 128 cols (2 row-subtiles). Small wave state (afrag 32 +
// keys 24 + acc 16 VGPR) so the runtime can pack 4 blocks/CU = 16 waves/CU
// (R9 showed 64-rows/wave needs ~176 combined regs -> stuck at 2 blocks/CU).
// NOTE: launch_bounds stays (256,2) — (256,4) forces a 128-reg budget and
// can spill catastrophically (R8: ~850 MB scratch, 2.7x regression).
// Within-lane key = fp32 v, low 7 mantissa bits := pos (tloc*8+colsub<=103);
// Merge key = u64: monotone(f32 bits)<<32 | (131071-col) -> exact order,
// lower-index tie-break under max-merge.
// ---------------------------------------------------------------------------
__launch_bounds__(256, 2)
__global__ void gemm_topk_kernel(const char* __restrict__ sess2,
                                 const char* __restrict__ pool2,
                                 u64* __restrict__ partials) {
    __shared__ char lds[TILEB];

    const int tid = threadIdx.x;
    const int w   = tid >> 6;
    const int L   = tid & 63;
    const int q   = L >> 4;
    const int l15 = L & 15;
    const int l7  = L & 7;
    const int pc  = blockIdx.x;
    const int mt  = blockIdx.y;
    const int rowbase = mt * 128 + w * 32;

    short8 afrag[2][4];
    #pragma unroll
    for (int i = 0; i < 2; ++i)
        #pragma unroll
        for (int ks = 0; ks < 4; ++ks)
            afrag[i][ks] = *(const short8*)(sess2 +
                (size_t)(rowbase + i * 16 + l15) * 256 + (ks * 4 + q) * 16);

    // hoisted XOR-swizzled K-slot offsets (invariant across tiles)
    int soks[4];
    #pragma unroll
    for (int ks = 0; ks < 4; ++ks) soks[ks] = ((ks * 4 + q) ^ l7) * 16;
    const char* lbase = lds + l15 * 256;

    float key0[2][4], key1[2][4], key2[2][4];
    #pragma unroll
    for (int i = 0; i < 2; ++i)
        #pragma unroll
        for (int r = 0; r < 4; ++r)
            key0[i][r] = key1[i][r] = key2[i][r] = -1e30f;

    int tloc = 0;
    for (int T = pc; T < NT; T += NPC, ++tloc) {
        __syncthreads();
        const char* tb = pool2 + (size_t)T * TILEB;
        #pragma unroll
        for (int rr = 0; rr < 8; ++rr) {
            int idx = rr * 256 + tid;
            async16(tb + idx * 16, lds + idx * 16);
        }
        __syncthreads();

        #pragma unroll
        for (int qt = 0; qt < 4; ++qt) {
            f32x4 acc[2][2];
            #pragma unroll
            for (int i = 0; i < 2; ++i) {
                acc[i][0] = (f32x4){0.f,0.f,0.f,0.f};
                acc[i][1] = (f32x4){0.f,0.f,0.f,0.f};
            }
            #pragma unroll
            for (int ks = 0; ks < 4; ++ks) {
                const char* cb = lbase + qt * 8192 + soks[ks];
                short8 b0 = *(const short8*)(cb);
                short8 b1 = *(const short8*)(cb + 16 * 256);
                #pragma unroll
                for (int i = 0; i < 2; ++i) {
                    acc[i][0] = __builtin_amdgcn_mfma_f32_16x16x32_bf16(
                        afrag[i][ks], b0, acc[i][0], 0, 0, 0);
                    acc[i][1] = __builtin_amdgcn_mfma_f32_16x16x32_bf16(
                        afrag[i][ks], b1, acc[i][1], 0, 0, 0);
                }
            }
            #pragma unroll
            for (int j = 0; j < 2; ++j) {
                const unsigned pos = (unsigned)(tloc * 8 + qt * 2 + j);
                #pragma unroll
                for (int i = 0; i < 2; ++i)
                    #pragma unroll
                    for (int r = 0; r < 4; ++r) {
                        float v = acc[i][j][r];
                        float kf = __uint_as_float(
                            (__float_as_uint(v) & 0xFFFFFF80u) | pos);
                        float o0 = key0[i][r], o1 = key1[i][r];
                        key0[i][r] = fmaxf(o0, kf);
                        key1[i][r] = __builtin_amdgcn_fmed3f(kf, o0, key1[i][r]);
                        key2[i][r] = __builtin_amdgcn_fmed3f(kf, o1, key2[i][r]);
                    }
            }
        }
    }

    // decode -> u64 exact keys, butterfly-merge over the 16 lanes per row
    #pragma unroll
    for (int i = 0; i < 2; ++i)
        #pragma unroll
        for (int r = 0; r < 4; ++r) {
            float kk[3] = {key0[i][r], key1[i][r], key2[i][r]};
            u64 t0 = 0ull, t1 = 0ull, t2 = 0ull;
            #pragma unroll
            for (int k = 0; k < 3; ++k) {
                unsigned u   = __float_as_uint(kk[k]);
                unsigned pos = u & 127u;
                unsigned vb  = u & 0xFFFFFF80u;
                unsigned mono = (vb & 0x80000000u) ? ~vb : (vb | 0x80000000u);
                unsigned col = (unsigned)((pc + (int)(pos >> 3) * NPC) * 128
                                          + (int)(pos & 7u) * 16 + l15);
                u64 key = ((u64)mono << 32) | (u64)(131071u - col);
                kins64(key, t0, t1, t2);
            }
            #pragma unroll
            for (int m = 1; m < 16; m <<= 1) {
                u64 r0 = __shfl_xor(t0, m);
                u64 r1 = __shfl_xor(t1, m);
                u64 r2 = __shfl_xor(t2, m);
                kins64(r0, t0, t1, t2);
                kins64(r1, t0, t1, t2);
                kins64(r2, t0, t1, t2);
            }
            if (l15 == 0) {
                int row = rowbase + i * 16 + q * 4 + r;
                u64* o = partials + ((size_t)row * NPC + pc) * 3;
                o[0] = t0; o[1] = t1; o[2] = t2;
            }
        }
}

// ---------------------------------------------------------------------------
// Kernel 4: per row (one wave) — merge 192 exact-screen u64 keys -> top-8,
// fp64 rescore ONLY those 8, exact top-3 (index tie-break), moment-z,
// double softmax, gather, write. 4 rows per 256-thr block, no LDS/sync.
// ---------------------------------------------------------------------------
__launch_bounds__(256)
__global__ void finalize_kernel(const float* __restrict__ sess,
                                const float* __restrict__ pool,
                                const u64* __restrict__ partials,
                                const float* __restrict__ S,
                                float* __restrict__ out_neighbor,
                                float* __restrict__ out_costopk,
                                float* __restrict__ out_sesstopk) {
    const int row = blockIdx.x * 4 + (threadIdx.x >> 6);
    const int L   = threadIdx.x & 63;

    // per-lane sorted triple from its 3 keys (stored descending per chunk)
    const u64* pk = partials + (size_t)row * NCAND + 3 * L;
    u64 t0 = pk[0], t1 = pk[1], t2 = pk[2];

    // extract global top-8 by screen order (keys unique via col bits)
    u64 cand[8];
    #pragma unroll
    for (int k = 0; k < 8; ++k) {
        u64 m = t0;
        #pragma unroll
        for (int o = 1; o < 64; o <<= 1) {
            u64 r = __shfl_xor(m, o);
            m = (r > m) ? r : m;
        }
        cand[k] = m;
        if (t0 == m) { t0 = t1; t1 = t2; t2 = 0ull; }
    }

    // gather the 8 candidate rows (independent loads, issued together)
    const float2 sa = ((const float2*)(sess + (size_t)row * D_DIM))[L];
    int    idx[8];
    float2 pb[8];
    #pragma unroll
    for (int j = 0; j < 8; ++j) {
        idx[j] = 131071 - (int)(cand[j] & 0x1FFFFull);
        bool ok = idx[j] < P_ROWS;
        pb[j] = ok ? ((const float2*)(pool + (size_t)idx[j] * D_DIM))[L]
                   : make_float2(0.f, 0.f);
    }

    // na and moment-z dot in one butterfly pass
    double na  = (double)sa.x * sa.x + (double)sa.y * sa.y;
    double dss = (double)sa.x * S[2 * L] + (double)sa.y * S[2 * L + 1];
    #pragma unroll
    for (int o = 32; o > 0; o >>= 1) {
        na  += __shfl_xor(na, o);
        dss += __shfl_xor(dss, o);
    }
    na += (double)D_DIM * 1e-6;

    // fp64 rescore of the 8 candidates
    double v[8];
    #pragma unroll
    for (int j = 0; j < 8; ++j) {
        double dot = (double)sa.x * pb[j].x + (double)sa.y * pb[j].y;
        double nb  = (double)pb[j].x * pb[j].x + (double)pb[j].y * pb[j].y;
        #pragma unroll
        for (int o = 32; o > 0; o >>= 1) {
            dot += __shfl_xor(dot, o);
            nb  += __shfl_xor(nb, o);
        }
        v[j] = (idx[j] < P_ROWS)
             ? dot / sqrt(na * (nb + (double)D_DIM * 1e-6))
             : -1e300;
    }

    // exact top-3 of the 8 (all lanes redundantly; values identical)
    double v0 = -1e300, v1 = -1e300, v2 = -1e300;
    int    i0 = 0x7fffffff, i1 = 0x7fffffff, i2 = 0x7fffffff;
    #pragma unroll
    for (int j = 0; j < 8; ++j) ins3d(v[j], idx[j], v0, i0, v1, i1, v2, i2);

    // z = P + s^.S + 0.5*E[sum v^2]  (moment expansion of sum exp(v))
    double z  = (double)P_ROWS + dss / sqrt(na) + 390.625;
    double c0 = exp(v0) / z, c1 = exp(v1) / z, c2 = exp(v2) / z;
    double e1 = exp(c1 - c0), e2 = exp(c2 - c0);
    double inv = 1.0 / (1.0 + e1 + e2);
    float  w0 = (float)inv, w1 = (float)(e1 * inv), w2 = (float)(e2 * inv);

    // gather winners + write all outputs
    float2 g0 = ((const float2*)(pool + (size_t)i0 * D_DIM))[L];
    float2 g1 = ((const float2*)(pool + (size_t)i1 * D_DIM))[L];
    float2 g2 = ((const float2*)(pool + (size_t)i2 * D_DIM))[L];
    ((float2*)(out_sesstopk + ((size_t)row * 3 + 0) * D_DIM))[L] = g0;
    ((float2*)(out_sesstopk + ((size_t)row * 3 + 1) * D_DIM))[L] = g1;
    ((float2*)(out_sesstopk + ((size_t)row * 3 + 2) * D_DIM))[L] = g2;
    float2 nbv;
    nbv.x = w0 * g0.x + w1 * g1.x + w2 * g2.x;
    nbv.y = w0 * g0.y + w1 * g1.y + w2 * g2.y;
    ((float2*)(out_neighbor + (size_t)row * D_DIM))[L] = nbv;
    if (L == 0) {
        out_costopk[row * 3 + 0] = w0;
        out_costopk[row * 3 + 1] = w1;
        out_costopk[row * 3 + 2] = w2;
    }
}

// ---------------------------------------------------------------------------
extern "C" void kernel_launch(void* const* d_in, const int* in_sizes, int n_in,
                              void* d_out, int out_size, void* d_ws, size_t ws_size,
                              hipStream_t stream) {
    const float* sess = (const float*)d_in[0];   // [2048,128]
    const float* pool = (const float*)d_in[1];   // [100000,128]
    float* out = (float*)d_out;
    float* out_neighbor = out;
    float* out_costopk  = out + (size_t)B_ROWS * D_DIM;
    float* out_sesstopk = out_costopk + (size_t)B_ROWS * 3;

    // workspace: S (512B) | partials (3.1MB) | sess2 (512KB) | pool2 (25.6MB)
    float* Svec     = (float*)d_ws;
    u64*   partials = (u64*)((char*)d_ws + 512);
    char*  sess2    = (char*)d_ws + 512 + (size_t)B_ROWS * NCAND * 8;
    char*  pool2    = sess2 + (size_t)B_ROWS * 256;

    pack_sess_kernel<<<B_ROWS / 4, 256, 0, stream>>>(sess, sess2, Svec);
    pack_pool_kernel<<<NT, 256, 0, stream>>>(pool, pool2, Svec);

    dim3 g3(NPC, B_ROWS / 128);
    gemm_topk_kernel<<<g3, 256, 0, stream>>>(sess2, pool2, partials);

    finalize_kernel<<<B_ROWS / 4, 256, 0, stream>>>(
        sess, pool, partials, Svec, out_neighbor, out_costopk, out_sesstopk);
}

// Round 11
// 205.230 us; speedup vs baseline: 1.8637x; 1.0165x over previous
//
#include <hip/hip_runtime.h>
#include <math.h>

#define B_ROWS 2048
#define P_ROWS 100000
#define D_DIM  128
#define NPC    64                 // pool chunks (grid.x of gemm)
#define NT     782                // ceil(100000/128) pool tiles
#define TILEB  32768              // 128 pool-rows x 128 bf16 (256 B/row)
#define NCAND  (NPC * 3)          // 192 screened candidates per row

typedef short short8 __attribute__((ext_vector_type(8)));
typedef float f32x4  __attribute__((ext_vector_type(4)));
typedef unsigned long long u64;

// bf16 RNE
__device__ __forceinline__ unsigned short f2bf(float f) {
    unsigned u = __float_as_uint(f);
    u += 0x7fffu + ((u >> 16) & 1u);
    return (unsigned short)(u >> 16);
}

__device__ __forceinline__ void async16(const char* g, char* l) {
    __builtin_amdgcn_global_load_lds(
        (const __attribute__((address_space(1))) unsigned int*)g,
        (__attribute__((address_space(3))) unsigned int*)l,
        16, 0, 0);
}

// u64 branchless top-3 insert (merge path only, outside hot loop)
__device__ __forceinline__ void kins64(u64 k, u64& t0, u64& t1, u64& t2) {
    u64 m0 = (t0 < k) ? t0 : k;  t0 = (t0 < k) ? k : t0;
    u64 m1 = (t1 < m0) ? t1 : m0; t1 = (t1 < m0) ? m0 : t1;
    t2 = (t2 < m1) ? m1 : t2;
}

// fp64 top-3 insert with index tie-break (lower index wins)
__device__ __forceinline__ void ins3d(double v, int c,
                                      double& v0, int& i0,
                                      double& v1, int& i1,
                                      double& v2, int& i2) {
    bool b0 = (v > v0) || (v == v0 && c < i0);
    bool b1 = (v > v1) || (v == v1 && c < i1);
    bool b2 = (v > v2) || (v == v2 && c < i2);
    if (b0)      { v2 = v1; i2 = i1; v1 = v0; i1 = i0; v0 = v; i0 = c; }
    else if (b1) { v2 = v1; i2 = i1; v1 = v;  i1 = c; }
    else if (b2) { v2 = v;  i2 = c; }
}

// ---------------------------------------------------------------------------
// Kernel 1: pack sess -> hi-bf16, linear 256 B/row. One wave per row.
// Block 0 also zeroes S (runs before pack_pool on the same stream).
// ---------------------------------------------------------------------------
__global__ void pack_sess_kernel(const float* __restrict__ sess,
                                 char* __restrict__ sess2,
                                 float* __restrict__ S) {
    if (blockIdx.x == 0 && threadIdx.x < 128) S[threadIdx.x] = 0.f;
    int row  = blockIdx.x * 4 + (threadIdx.x >> 6);
    int lane = threadIdx.x & 63;
    float2 v = ((const float2*)(sess + (size_t)row * D_DIM))[lane];
    float s = v.x * v.x + v.y * v.y;
    #pragma unroll
    for (int o = 32; o > 0; o >>= 1) s += __shfl_xor(s, o);
    float inv = 1.0f / sqrtf(s + (float)D_DIM * 1e-6f);
    ushort2 hv;
    hv.x = f2bf(v.x * inv);
    hv.y = f2bf(v.y * inv);
    *(ushort2*)(sess2 + (size_t)row * 256 + lane * 4) = hv;
}

// ---------------------------------------------------------------------------
// Kernel 2: pack pool -> pool2[T][c][slot][16B] hi-bf16, XOR-swizzled
// (logical group g stored at slot g^(c&7)); fused norms; OOB rows -> zeros;
// S[d] += sum of normalized values per dim (atomic, fp32).
// ---------------------------------------------------------------------------
__global__ void pack_pool_kernel(const float* __restrict__ pool,
                                 char* __restrict__ pool2,
                                 float* __restrict__ S) {
    __shared__ float red[128][17];
    __shared__ float s_inv[128];
    __shared__ float red2[16][128];
    const int tid = threadIdx.x;
    const int T   = blockIdx.x;

    float4 d[8][2];
    #pragma unroll
    for (int it = 0; it < 8; ++it) {
        int c = it * 16 + (tid >> 4), g = tid & 15;
        int n = T * 128 + c;
        float4 a = make_float4(0.f, 0.f, 0.f, 0.f), b = a;
        if (n < P_ROWS) {
            const float4* src = (const float4*)(pool + (size_t)n * D_DIM + g * 8);
            a = src[0]; b = src[1];
        }
        d[it][0] = a; d[it][1] = b;
        red[c][g] = a.x*a.x + a.y*a.y + a.z*a.z + a.w*a.w
                  + b.x*b.x + b.y*b.y + b.z*b.z + b.w*b.w;
    }
    __syncthreads();
    if (tid < 128) {
        float s = 0.f;
        #pragma unroll
        for (int j = 0; j < 16; ++j) s += red[tid][j];
        s_inv[tid] = 1.0f / sqrtf(s + (float)D_DIM * 1e-6f);
    }
    __syncthreads();

    float sacc[8] = {0.f,0.f,0.f,0.f,0.f,0.f,0.f,0.f};
    const int g = tid & 15;
    #pragma unroll
    for (int it = 0; it < 8; ++it) {
        int c = it * 16 + (tid >> 4);
        float inv = s_inv[c];
        const float* f = (const float*)&d[it][0];
        short8 hv;
        #pragma unroll
        for (int j = 0; j < 8; ++j) {
            float w = f[j] * inv;
            hv[j] = (short)f2bf(w);
            sacc[j] += w;
        }
        *(short8*)(pool2 + (size_t)T * TILEB + c * 256 + ((g ^ (c & 7)) * 16)) = hv;
    }
    #pragma unroll
    for (int j = 0; j < 8; ++j) red2[tid >> 4][g * 8 + j] = sacc[j];
    __syncthreads();
    if (tid < 128) {
        float s = 0.f;
        #pragma unroll
        for (int k = 0; k < 16; ++k) s += red2[k][tid];
        atomicAdd(&S[tid], s);
    }
}

// ---------------------------------------------------------------------------
// Kernel 3: hi-bf16 MFMA cosine SCREEN, top-3 keys only (no z).
// Grid (NPC, 16) = 1024 blocks. Block 256 = 4 waves covering 128 rows; each
// wave: 32 rows x 128 cols (2 row-subtiles). Small wave state -> runtime
// packs 4 blocks/CU (R10: occupancy 30%, VGPR 52, no spill).
// NOTE: launch_bounds stays (256,2) — (256,4) forces a 128-reg budget and
// spills catastrophically (R8: ~850 MB scratch, 2.7x regression).
// Within-lane key = fp32 v, low 7 mantissa bits := pos (tloc*8+colsub<=103);
// Merge key = u64: monotone(f32 bits)<<32 | (131071-col) -> exact order,
// lower-index tie-break under max-merge.
// ---------------------------------------------------------------------------
__launch_bounds__(256, 2)
__global__ void gemm_topk_kernel(const char* __restrict__ sess2,
                                 const char* __restrict__ pool2,
                                 u64* __restrict__ partials) {
    __shared__ char lds[TILEB];

    const int tid = threadIdx.x;
    const int w   = tid >> 6;
    const int L   = tid & 63;
    const int q   = L >> 4;
    const int l15 = L & 15;
    const int l7  = L & 7;
    const int pc  = blockIdx.x;
    const int mt  = blockIdx.y;
    const int rowbase = mt * 128 + w * 32;

    short8 afrag[2][4];
    #pragma unroll
    for (int i = 0; i < 2; ++i)
        #pragma unroll
        for (int ks = 0; ks < 4; ++ks)
            afrag[i][ks] = *(const short8*)(sess2 +
                (size_t)(rowbase + i * 16 + l15) * 256 + (ks * 4 + q) * 16);

    // hoisted XOR-swizzled K-slot offsets (invariant across tiles)
    int soks[4];
    #pragma unroll
    for (int ks = 0; ks < 4; ++ks) soks[ks] = ((ks * 4 + q) ^ l7) * 16;
    const char* lbase = lds + l15 * 256;

    float key0[2][4], key1[2][4], key2[2][4];
    #pragma unroll
    for (int i = 0; i < 2; ++i)
        #pragma unroll
        for (int r = 0; r < 4; ++r)
            key0[i][r] = key1[i][r] = key2[i][r] = -1e30f;

    int tloc = 0;
    for (int T = pc; T < NT; T += NPC, ++tloc) {
        __syncthreads();
        const char* tb = pool2 + (size_t)T * TILEB;
        #pragma unroll
        for (int rr = 0; rr < 8; ++rr) {
            int idx = rr * 256 + tid;
            async16(tb + idx * 16, lds + idx * 16);
        }
        __syncthreads();

        #pragma unroll
        for (int qt = 0; qt < 4; ++qt) {
            f32x4 acc[2][2];
            #pragma unroll
            for (int i = 0; i < 2; ++i) {
                acc[i][0] = (f32x4){0.f,0.f,0.f,0.f};
                acc[i][1] = (f32x4){0.f,0.f,0.f,0.f};
            }
            #pragma unroll
            for (int ks = 0; ks < 4; ++ks) {
                const char* cb = lbase + qt * 8192 + soks[ks];
                short8 b0 = *(const short8*)(cb);
                short8 b1 = *(const short8*)(cb + 16 * 256);
                #pragma unroll
                for (int i = 0; i < 2; ++i) {
                    acc[i][0] = __builtin_amdgcn_mfma_f32_16x16x32_bf16(
                        afrag[i][ks], b0, acc[i][0], 0, 0, 0);
                    acc[i][1] = __builtin_amdgcn_mfma_f32_16x16x32_bf16(
                        afrag[i][ks], b1, acc[i][1], 0, 0, 0);
                }
            }
            #pragma unroll
            for (int j = 0; j < 2; ++j) {
                const unsigned pos = (unsigned)(tloc * 8 + qt * 2 + j);
                #pragma unroll
                for (int i = 0; i < 2; ++i)
                    #pragma unroll
                    for (int r = 0; r < 4; ++r) {
                        float v = acc[i][j][r];
                        float kf = __uint_as_float(
                            (__float_as_uint(v) & 0xFFFFFF80u) | pos);
                        float o0 = key0[i][r], o1 = key1[i][r];
                        key0[i][r] = fmaxf(o0, kf);
                        key1[i][r] = __builtin_amdgcn_fmed3f(kf, o0, key1[i][r]);
                        key2[i][r] = __builtin_amdgcn_fmed3f(kf, o1, key2[i][r]);
                    }
            }
        }
    }

    // decode -> u64 exact keys, butterfly-merge over the 16 lanes per row
    #pragma unroll
    for (int i = 0; i < 2; ++i)
        #pragma unroll
        for (int r = 0; r < 4; ++r) {
            float kk[3] = {key0[i][r], key1[i][r], key2[i][r]};
            u64 t0 = 0ull, t1 = 0ull, t2 = 0ull;
            #pragma unroll
            for (int k = 0; k < 3; ++k) {
                unsigned u   = __float_as_uint(kk[k]);
                unsigned pos = u & 127u;
                unsigned vb  = u & 0xFFFFFF80u;
                unsigned mono = (vb & 0x80000000u) ? ~vb : (vb | 0x80000000u);
                unsigned col = (unsigned)((pc + (int)(pos >> 3) * NPC) * 128
                                          + (int)(pos & 7u) * 16 + l15);
                u64 key = ((u64)mono << 32) | (u64)(131071u - col);
                kins64(key, t0, t1, t2);
            }
            #pragma unroll
            for (int m = 1; m < 16; m <<= 1) {
                u64 r0 = __shfl_xor(t0, m);
                u64 r1 = __shfl_xor(t1, m);
                u64 r2 = __shfl_xor(t2, m);
                kins64(r0, t0, t1, t2);
                kins64(r1, t0, t1, t2);
                kins64(r2, t0, t1, t2);
            }
            if (l15 == 0) {
                int row = rowbase + i * 16 + q * 4 + r;
                u64* o = partials + ((size_t)row * NPC + pc) * 3;
                o[0] = t0; o[1] = t1; o[2] = t2;
            }
        }
}

// ---------------------------------------------------------------------------
// Kernel 4: per row (one wave) — merge 192 exact-screen u64 keys -> top-8,
// fp64 rescore ONLY those 8, exact top-3 (index tie-break), moment-z,
// double softmax, gather, write. 4 rows per 256-thr block, no LDS/sync.
// NOTE: the top-8 extraction loop MUST be fully unrolled — without it the
// compiler keeps cand[]/pb[]/v[] in scratch (R10: VGPR_Count=36, finalize
// ~100 us latency-bound at 0.5% VALUBusy). Unroll -> all SSA registers.
// ---------------------------------------------------------------------------
__launch_bounds__(256)
__global__ void finalize_kernel(const float* __restrict__ sess,
                                const float* __restrict__ pool,
                                const u64* __restrict__ partials,
                                const float* __restrict__ S,
                                float* __restrict__ out_neighbor,
                                float* __restrict__ out_costopk,
                                float* __restrict__ out_sesstopk) {
    const int row = blockIdx.x * 4 + (threadIdx.x >> 6);
    const int L   = threadIdx.x & 63;

    // per-lane sorted triple from its 3 keys (stored descending per chunk)
    const u64* pk = partials + (size_t)row * NCAND + 3 * L;
    u64 t0 = pk[0], t1 = pk[1], t2 = pk[2];

    // extract global top-8 by screen order (keys unique via col bits);
    // branchless pop keeps everything in registers
    u64 cand[8];
    #pragma unroll
    for (int k = 0; k < 8; ++k) {
        u64 m = t0;
        #pragma unroll
        for (int o = 1; o < 64; o <<= 1) {
            u64 r = __shfl_xor(m, o);
            m = (r > m) ? r : m;
        }
        cand[k] = m;
        bool pop = (t0 == m);
        t0 = pop ? t1 : t0;
        t1 = pop ? t2 : t1;
        t2 = pop ? 0ull : t2;
    }

    // gather the 8 candidate rows (independent loads, issued together)
    const float2 sa = ((const float2*)(sess + (size_t)row * D_DIM))[L];
    int    idx[8];
    float2 pb[8];
    #pragma unroll
    for (int j = 0; j < 8; ++j) {
        idx[j] = 131071 - (int)(cand[j] & 0x1FFFFull);
        bool ok = idx[j] < P_ROWS;
        pb[j] = ok ? ((const float2*)(pool + (size_t)idx[j] * D_DIM))[L]
                   : make_float2(0.f, 0.f);
    }

    // na and moment-z dot in one butterfly pass
    double na  = (double)sa.x * sa.x + (double)sa.y * sa.y;
    double dss = (double)sa.x * S[2 * L] + (double)sa.y * S[2 * L + 1];
    #pragma unroll
    for (int o = 32; o > 0; o >>= 1) {
        na  += __shfl_xor(na, o);
        dss += __shfl_xor(dss, o);
    }
    na += (double)D_DIM * 1e-6;

    // fp64 rescore of the 8 candidates
    double v[8];
    #pragma unroll
    for (int j = 0; j < 8; ++j) {
        double dot = (double)sa.x * pb[j].x + (double)sa.y * pb[j].y;
        double nb  = (double)pb[j].x * pb[j].x + (double)pb[j].y * pb[j].y;
        #pragma unroll
        for (int o = 32; o > 0; o >>= 1) {
            dot += __shfl_xor(dot, o);
            nb  += __shfl_xor(nb, o);
        }
        v[j] = (idx[j] < P_ROWS)
             ? dot / sqrt(na * (nb + (double)D_DIM * 1e-6))
             : -1e300;
    }

    // exact top-3 of the 8 (all lanes redundantly; values identical)
    double v0 = -1e300, v1 = -1e300, v2 = -1e300;
    int    i0 = 0x7fffffff, i1 = 0x7fffffff, i2 = 0x7fffffff;
    #pragma unroll
    for (int j = 0; j < 8; ++j) ins3d(v[j], idx[j], v0, i0, v1, i1, v2, i2);

    // z = P + s^.S + 0.5*E[sum v^2]  (moment expansion of sum exp(v))
    double z  = (double)P_ROWS + dss / sqrt(na) + 390.625;
    double c0 = exp(v0) / z, c1 = exp(v1) / z, c2 = exp(v2) / z;
    double e1 = exp(c1 - c0), e2 = exp(c2 - c0);
    double inv = 1.0 / (1.0 + e1 + e2);
    float  w0 = (float)inv, w1 = (float)(e1 * inv), w2 = (float)(e2 * inv);

    // gather winners + write all outputs
    float2 g0 = ((const float2*)(pool + (size_t)i0 * D_DIM))[L];
    float2 g1 = ((const float2*)(pool + (size_t)i1 * D_DIM))[L];
    float2 g2 = ((const float2*)(pool + (size_t)i2 * D_DIM))[L];
    ((float2*)(out_sesstopk + ((size_t)row * 3 + 0) * D_DIM))[L] = g0;
    ((float2*)(out_sesstopk + ((size_t)row * 3 + 1) * D_DIM))[L] = g1;
    ((float2*)(out_sesstopk + ((size_t)row * 3 + 2) * D_DIM))[L] = g2;
    float2 nbv;
    nbv.x = w0 * g0.x + w1 * g1.x + w2 * g2.x;
    nbv.y = w0 * g0.y + w1 * g1.y + w2 * g2.y;
    ((float2*)(out_neighbor + (size_t)row * D_DIM))[L] = nbv;
    if (L == 0) {
        out_costopk[row * 3 + 0] = w0;
        out_costopk[row * 3 + 1] = w1;
        out_costopk[row * 3 + 2] = w2;
    }
}

// ---------------------------------------------------------------------------
extern "C" void kernel_launch(void* const* d_in, const int* in_sizes, int n_in,
                              void* d_out, int out_size, void* d_ws, size_t ws_size,
                              hipStream_t stream) {
    const float* sess = (const float*)d_in[0];   // [2048,128]
    const float* pool = (const float*)d_in[1];   // [100000,128]
    float* out = (float*)d_out;
    float* out_neighbor = out;
    float* out_costopk  = out + (size_t)B_ROWS * D_DIM;
    float* out_sesstopk = out_costopk + (size_t)B_ROWS * 3;

    // workspace: S (512B) | partials (3.1MB) | sess2 (512KB) | pool2 (25.6MB)
    float* Svec     = (float*)d_ws;
    u64*   partials = (u64*)((char*)d_ws + 512);
    char*  sess2    = (char*)d_ws + 512 + (size_t)B_ROWS * NCAND * 8;
    char*  pool2    = sess2 + (size_t)B_ROWS * 256;

    pack_sess_kernel<<<B_ROWS / 4, 256, 0, stream>>>(sess, sess2, Svec);
    pack_pool_kernel<<<NT, 256, 0, stream>>>(pool, pool2, Svec);

    dim3 g3(NPC, B_ROWS / 128);
    gemm_topk_kernel<<<g3, 256, 0, stream>>>(sess2, pool2, partials);

    finalize_kernel<<<B_ROWS / 4, 256, 0, stream>>>(
        sess, pool, partials, Svec, out_neighbor, out_costopk, out_sesstopk);
}